// Round 2
// baseline (747.877 us; speedup 1.0000x reference)
//
#include <hip/hip_runtime.h>

// VariableSelection (TFT-style) on gfx950. ALL I/O f32; bf16 MFMA internally.
// B=128 S=64 F=32 D=128 U=128 DS=128 DIN=262272, KMAIN=S*F*D=262144

typedef unsigned short u16;
typedef __attribute__((ext_vector_type(4))) u16 u16x4;
typedef __attribute__((ext_vector_type(8))) u16 u16x8;
typedef __attribute__((ext_vector_type(8))) __bf16 bf16x8;
typedef __attribute__((ext_vector_type(4))) float f32x4;

__device__ __forceinline__ u16 f2bf(float f) {
  unsigned int x = __float_as_uint(f);
  return (u16)((x + 0x7fffu + ((x >> 16) & 1u)) >> 16);  // RNE
}
__device__ __forceinline__ float eluf(float x) { return x > 0.f ? x : __expf(x) - 1.f; }
__device__ __forceinline__ float sigmoidf_(float x) { return 1.f / (1.f + __expf(-x)); }

#define MFMA_BF16(a, b, c) __builtin_amdgcn_mfma_f32_16x16x32_bf16((a), (b), (c), 0, 0, 0)

// ---------------------------------------------------------------------------
// K0: convert per-feature GRN weights f32 -> bf16, transposed [n][k].
// grid 128 = f*4+mat, block 128 (thread = n)
// ---------------------------------------------------------------------------
__global__ __launch_bounds__(128) void k0_prep(
    const float* __restrict__ fWe, const float* __restrict__ fWl,
    const float* __restrict__ fWgl, const float* __restrict__ fWgs,
    u16* __restrict__ wT)
{
  const int b = blockIdx.x, f = b >> 2, mat = b & 3;
  const float* srcs[4] = {fWe, fWl, fWgl, fWgs};
  const float* src = srcs[mat] + (size_t)f * 16384;   // [k=128][n=128]
  u16* dst = wT + (size_t)b * 16384;                  // [n=128][k=128]
  const int n = threadIdx.x;
  for (int k8 = 0; k8 < 16; ++k8) {
    u16x8 p;
#pragma unroll
    for (int j = 0; j < 8; ++j) p[j] = f2bf(src[(k8 * 8 + j) * 128 + n]);
    *(u16x8*)&dst[n * 128 + k8 * 8] = p;
  }
}

// ---------------------------------------------------------------------------
// K1: fused split-K  he_pre = v[:, :262144] @ cWe,  res_pre = v @ cWp
// grid 256 k-blocks; block 512 thr (8 waves); per block M=128, N=128(x2), K=1024
// A tile shared between both matrices (inp read once).
// ---------------------------------------------------------------------------
__global__ __launch_bounds__(512) void k1_bigmm(
    const float* __restrict__ inp, const float* __restrict__ cWe,
    const float* __restrict__ cWp, float* __restrict__ outE, float* __restrict__ outP)
{
  __shared__ __align__(16) u16 xA[128][72];   // v tile [m][k=64] bf16 (+pad)
  __shared__ __align__(16) u16 wE[128][72];   // cWe tile transposed [n][k]
  __shared__ __align__(16) u16 wP[128][72];   // cWp tile transposed [n][k]
  const int t = threadIdx.x;
  const int lane = t & 63, wv = t >> 6, quad = lane >> 4, l16 = lane & 15;
  const int half = t >> 8;               // W-staging: 0 -> E, 1 -> P
  const int tt = t & 255, kb4 = tt >> 4, nbw = tt & 15;
  const float* Wsel = half ? cWp : cWe;

  f32x4 accE[8], accP[8];
#pragma unroll
  for (int n = 0; n < 8; ++n)
#pragma unroll
    for (int r = 0; r < 4; ++r) { accE[n][r] = 0.f; accP[n][r] = 0.f; }

  const size_t kbase = (size_t)blockIdx.x * 1024;
  for (int it = 0; it < 16; ++it) {
    const size_t kk = kbase + (size_t)it * 64;
    // ---- stage A: 128 rows x 64 k (f32 -> bf16), 4 float4/thread, coalesced
#pragma unroll
    for (int i = 0; i < 4; ++i) {
      const int fu = t + i * 512;
      const int row = fu >> 4, fo = fu & 15;
      const float4 v = *(const float4*)(inp + (size_t)row * 262144 + kk + fo * 4);
      u16x4 p; p[0] = f2bf(v.x); p[1] = f2bf(v.y); p[2] = f2bf(v.z); p[3] = f2bf(v.w);
      *(u16x4*)&xA[row][fo * 4] = p;
    }
    // ---- stage W (own matrix): 4k x 8n sub-block transpose per thread
    float fr[4][8];
#pragma unroll
    for (int j = 0; j < 4; ++j) {
      const float4 v0 = *(const float4*)(Wsel + (kk + (size_t)(kb4 * 4 + j)) * 128 + nbw * 8);
      const float4 v1 = *(const float4*)(Wsel + (kk + (size_t)(kb4 * 4 + j)) * 128 + nbw * 8 + 4);
      fr[j][0] = v0.x; fr[j][1] = v0.y; fr[j][2] = v0.z; fr[j][3] = v0.w;
      fr[j][4] = v1.x; fr[j][5] = v1.y; fr[j][6] = v1.z; fr[j][7] = v1.w;
    }
    {
      u16 (*Wl)[72] = half ? wP : wE;
#pragma unroll
      for (int c = 0; c < 8; ++c) {
        u16x4 col;
#pragma unroll
        for (int j = 0; j < 4; ++j) col[j] = f2bf(fr[j][c]);
        *(u16x4*)&Wl[nbw * 8 + c][kb4 * 4] = col;
      }
    }
    __syncthreads();
    // ---- MFMA: wave wv owns rows 16wv..16wv+15, all 128 cols, both matrices
#pragma unroll
    for (int ks = 0; ks < 2; ++ks) {
      const int ko = ks * 32 + quad * 8;
      const bf16x8 a = *(const bf16x8*)&xA[16 * wv + l16][ko];
#pragma unroll
      for (int nt = 0; nt < 8; ++nt) {
        const bf16x8 bE = *(const bf16x8*)&wE[nt * 16 + l16][ko];
        const bf16x8 bP = *(const bf16x8*)&wP[nt * 16 + l16][ko];
        accE[nt] = MFMA_BF16(a, bE, accE[nt]);
        accP[nt] = MFMA_BF16(a, bP, accP[nt]);
      }
    }
    __syncthreads();
  }
  // C/D layout: col = lane&15, row = quad*4 + reg
#pragma unroll
  for (int nt = 0; nt < 8; ++nt) {
    const int col = nt * 16 + l16;
#pragma unroll
    for (int r = 0; r < 4; ++r) {
      const int row = 16 * wv + quad * 4 + r;
      atomicAdd(&outE[row * 128 + col], accE[nt][r]);
      atomicAdd(&outP[row * 128 + col], accP[nt][r]);
    }
  }
}

// ---------------------------------------------------------------------------
// K1b: static tail + concat-GRN chain + LN + softmax -> w[B,F]
// grid 128 (block = batch row), block 128 (thread = unit)
// ---------------------------------------------------------------------------
__global__ __launch_bounds__(128) void k1b_small(
    const float* __restrict__ stat,
    const float* __restrict__ cWe, const float* __restrict__ cbe,
    const float* __restrict__ cWl, const float* __restrict__ cbl,
    const float* __restrict__ cWgl, const float* __restrict__ cbgl,
    const float* __restrict__ cWgs, const float* __restrict__ cbgs,
    const float* __restrict__ cgam, const float* __restrict__ cbet,
    const float* __restrict__ cWp, const float* __restrict__ cbp,
    const float* __restrict__ Ws, const float* __restrict__ bs,
    const float* __restrict__ preE, const float* __restrict__ preP,
    float* __restrict__ wout)
{
  const int b = blockIdx.x, t = threadIdx.x;
  __shared__ float shS[128], shA[128], shB[128], red[4];
  shS[t] = stat[b * 128 + t];
  __syncthreads();
  float he = preE[b * 128 + t] + cbe[t];
  float rs = preP[b * 128 + t] + cbp[t];
  for (int d = 0; d < 128; ++d) {
    const float sv = shS[d];
    he += sv * cWe[(size_t)(262144 + d) * 128 + t];
    rs += sv * cWp[(size_t)(262144 + d) * 128 + t];
  }
  he = eluf(he);
  shA[t] = he;
  __syncthreads();
  float h2 = cbl[t];
  for (int d = 0; d < 128; ++d) h2 += shA[d] * cWl[d * 128 + t];
  shB[t] = h2;
  __syncthreads();
  float gl = cbgl[t], gs = cbgs[t];
  for (int d = 0; d < 128; ++d) {
    const float hv = shB[d];
    gl += hv * cWgl[d * 128 + t];
    gs += hv * cWgs[d * 128 + t];
  }
  const float z = rs + gl * sigmoidf_(gs);
  float s = z, q = z * z;
#pragma unroll
  for (int off = 32; off >= 1; off >>= 1) { s += __shfl_xor(s, off); q += __shfl_xor(q, off); }
  if ((t & 63) == 0) { red[(t >> 6) * 2] = s; red[(t >> 6) * 2 + 1] = q; }
  __syncthreads();
  const float S = red[0] + red[2], Q = red[1] + red[3];
  const float mean = S * (1.f / 128.f);
  const float var = Q * (1.f / 128.f) - mean * mean;
  const float rstd = rsqrtf(var + 1e-3f);
  const float y = (z - mean) * rstd * cgam[t] + cbet[t];
  shA[t] = y;
  __syncthreads();
  if (t < 32) {
    float sj = bs[t];
    for (int u = 0; u < 128; ++u) sj += shA[u] * Ws[u * 32 + t];
    float m = sj;
#pragma unroll
    for (int off = 16; off >= 1; off >>= 1) m = fmaxf(m, __shfl_xor(m, off));
    const float e = __expf(sj - m);
    float se = e;
#pragma unroll
    for (int off = 16; off >= 1; off >>= 1) se += __shfl_xor(se, off);
    wout[b * 32 + t] = e / se;
  }
}

// ---------------------------------------------------------------------------
// K2 helpers
// ---------------------------------------------------------------------------
__device__ __forceinline__ void stage_wt(const u16* __restrict__ src, int kh,
                                         u16 WT[][72], int t)
{
  // src: pre-transposed bf16 [n=128][k=128]; copy k-half kh into WT[n][0..63]
#pragma unroll
  for (int i = 0; i < 4; ++i) {
    const int u = t + i * 256;
    const int n = u >> 3, k8 = u & 7;
    *(u16x8*)&WT[n][k8 * 8] = *(const u16x8*)(src + n * 128 + kh + k8 * 8);
  }
}

__device__ __forceinline__ void mm_half(const u16 A[][136], const u16 WT[][72],
                                        int wv, int quad, int l16, int kh, f32x4 acc[8])
{
#pragma unroll
  for (int ks = 0; ks < 2; ++ks) {
    const int kol = ks * 32 + quad * 8;
    const bf16x8 a = *(const bf16x8*)&A[16 * wv + l16][kh + kol];
#pragma unroll
    for (int nt = 0; nt < 8; ++nt) {
      const bf16x8 b = *(const bf16x8*)&WT[nt * 16 + l16][kol];
      acc[nt] = MFMA_BF16(a, b, acc[nt]);
    }
  }
}

// ---------------------------------------------------------------------------
// K2: per-feature GRN + LN + weighted accumulate into f32 d_out.
// grid 4096 = f(slow) x bb(fast: blockIdx&127); block 256 thr; M=64 (one b), N=128
// wave wv owns rows 16wv..16wv+15 (full row per lane-quad -> shuffle LN).
// ---------------------------------------------------------------------------
__global__ __launch_bounds__(256) void k2_grn(
    const float* __restrict__ inp, const u16* __restrict__ wT,
    const float* __restrict__ fbe, const float* __restrict__ fbl,
    const float* __restrict__ fbgl, const float* __restrict__ fbgs,
    const float* __restrict__ fgam, const float* __restrict__ fbet,
    const float* __restrict__ wsel, float* __restrict__ out)
{
  __shared__ __align__(16) u16 xA[64][136];   // x tile bf16
  __shared__ __align__(16) u16 hA[64][136];   // h then h2
  __shared__ __align__(16) u16 WT[128][72];   // weight k-half, transposed [n][k]
  const int t = threadIdx.x;
  const int lane = t & 63, wv = t >> 6, quad = lane >> 4, l16 = lane & 15;
  const int bb = blockIdx.x & 127, f = blockIdx.x >> 7;
  const float wb = wsel[bb * 32 + f];
  const u16* wf = wT + (size_t)f * 65536;     // 4 mats x [128][128]

  // stage x tile rows s=0..63, cols f*128..+128 (f32 -> bf16)
#pragma unroll
  for (int i = 0; i < 8; ++i) {
    const int u = t + i * 256;
    const int row = u >> 5, fo = u & 31;
    const float4 v = *(const float4*)(inp + (size_t)(bb * 64 + row) * 4096 + f * 128 + fo * 4);
    u16x4 p; p[0] = f2bf(v.x); p[1] = f2bf(v.y); p[2] = f2bf(v.z); p[3] = f2bf(v.w);
    *(u16x4*)&xA[row][fo * 4] = p;
  }

  f32x4 acc[8], glr[8];
#define ZERO_ACC() do { _Pragma("unroll") \
  for (int n_ = 0; n_ < 8; ++n_) { acc[n_][0]=0.f; acc[n_][1]=0.f; acc[n_][2]=0.f; acc[n_][3]=0.f; } } while (0)

  // ---- stage 1: h = elu(x @ We + be) -> hA
  stage_wt(wf, 0, WT, t);
  __syncthreads();
  ZERO_ACC();
  mm_half(xA, WT, wv, quad, l16, 0, acc);
  __syncthreads();
  stage_wt(wf, 64, WT, t);
  __syncthreads();
  mm_half(xA, WT, wv, quad, l16, 64, acc);
#pragma unroll
  for (int nt = 0; nt < 8; ++nt) {
    const int col = nt * 16 + l16;
    const float bv = fbe[f * 128 + col];
#pragma unroll
    for (int r = 0; r < 4; ++r)
      hA[16 * wv + quad * 4 + r][col] = f2bf(eluf(acc[nt][r] + bv));
  }
  __syncthreads();

  // ---- stage 2: h2 = h @ Wl + bl -> hA (waves touch only their own rows)
  stage_wt(wf + 16384, 0, WT, t);
  __syncthreads();
  ZERO_ACC();
  mm_half(hA, WT, wv, quad, l16, 0, acc);
  __syncthreads();
  stage_wt(wf + 16384, 64, WT, t);
  __syncthreads();
  mm_half(hA, WT, wv, quad, l16, 64, acc);
#pragma unroll
  for (int nt = 0; nt < 8; ++nt) {
    const int col = nt * 16 + l16;
    const float bv = fbl[f * 128 + col];
#pragma unroll
    for (int r = 0; r < 4; ++r)
      hA[16 * wv + quad * 4 + r][col] = f2bf(acc[nt][r] + bv);
  }
  __syncthreads();

  // ---- stage 3: gl = h2 @ Wgl + bgl (kept in regs)
  stage_wt(wf + 2 * 16384, 0, WT, t);
  __syncthreads();
  ZERO_ACC();
  mm_half(hA, WT, wv, quad, l16, 0, acc);
  __syncthreads();
  stage_wt(wf + 2 * 16384, 64, WT, t);
  __syncthreads();
  mm_half(hA, WT, wv, quad, l16, 64, acc);
#pragma unroll
  for (int nt = 0; nt < 8; ++nt) {
    const int col = nt * 16 + l16;
    const float bv = fbgl[f * 128 + col];
#pragma unroll
    for (int r = 0; r < 4; ++r) glr[nt][r] = acc[nt][r] + bv;
  }
  __syncthreads();

  // ---- stage 4: gs = h2 @ Wgs + bgs
  stage_wt(wf + 3 * 16384, 0, WT, t);
  __syncthreads();
  ZERO_ACC();
  mm_half(hA, WT, wv, quad, l16, 0, acc);
  __syncthreads();
  stage_wt(wf + 3 * 16384, 64, WT, t);
  __syncthreads();
  mm_half(hA, WT, wv, quad, l16, 64, acc);

  // ---- epilogue: g = gl*sigmoid(gs); z = x + g; LN per row; out += wb * xg
#pragma unroll
  for (int nt = 0; nt < 8; ++nt) {
    const int col = nt * 16 + l16;
    const float bv = fbgs[f * 128 + col];
#pragma unroll
    for (int r = 0; r < 4; ++r) {
      const float g = glr[nt][r] * sigmoidf_(acc[nt][r] + bv);
      const float x = __uint_as_float(((unsigned int)xA[16 * wv + quad * 4 + r][col]) << 16);
      acc[nt][r] = x + g;  // z
    }
  }
  float sm[4], sq[4];
#pragma unroll
  for (int r = 0; r < 4; ++r) {
    float s = 0.f, q = 0.f;
#pragma unroll
    for (int nt = 0; nt < 8; ++nt) { const float z = acc[nt][r]; s += z; q += z * z; }
    sm[r] = s; sq[r] = q;
  }
#pragma unroll
  for (int off = 1; off <= 8; off <<= 1)
#pragma unroll
    for (int r = 0; r < 4; ++r) { sm[r] += __shfl_xor(sm[r], off); sq[r] += __shfl_xor(sq[r], off); }
  float mean[4], rstd[4];
#pragma unroll
  for (int r = 0; r < 4; ++r) {
    mean[r] = sm[r] * (1.f / 128.f);
    const float var = sq[r] * (1.f / 128.f) - mean[r] * mean[r];
    rstd[r] = rsqrtf(var + 1e-3f);
  }
#pragma unroll
  for (int nt = 0; nt < 8; ++nt) {
    const int col = nt * 16 + l16;
    const float gam = fgam[f * 128 + col];
    const float bet = fbet[f * 128 + col];
#pragma unroll
    for (int r = 0; r < 4; ++r) {
      const float xg = (acc[nt][r] - mean[r]) * rstd[r] * gam + bet;
      const int grow = bb * 64 + 16 * wv + quad * 4 + r;
      atomicAdd(&out[(size_t)grow * 128 + col], wb * xg);
    }
  }
#undef ZERO_ACC
}

extern "C" void kernel_launch(void* const* d_in, const int* in_sizes, int n_in,
                              void* d_out, int out_size, void* d_ws, size_t ws_size,
                              hipStream_t stream)
{
  const float* inp    = (const float*)d_in[0];
  const float* stat   = (const float*)d_in[1];
  const float* cWe    = (const float*)d_in[2];
  const float* cbe    = (const float*)d_in[3];
  const float* cWl    = (const float*)d_in[4];
  const float* cbl    = (const float*)d_in[5];
  const float* cWgl   = (const float*)d_in[6];
  const float* cbgl   = (const float*)d_in[7];
  const float* cWgs   = (const float*)d_in[8];
  const float* cbgs   = (const float*)d_in[9];
  const float* cgamma = (const float*)d_in[10];
  const float* cbeta  = (const float*)d_in[11];
  const float* cWp    = (const float*)d_in[12];
  const float* cbp    = (const float*)d_in[13];
  const float* Ws     = (const float*)d_in[14];
  const float* bs     = (const float*)d_in[15];
  const float* fWe    = (const float*)d_in[16];
  const float* fbe    = (const float*)d_in[17];
  const float* fWl    = (const float*)d_in[18];
  const float* fbl    = (const float*)d_in[19];
  const float* fWgl   = (const float*)d_in[20];
  const float* fbgl   = (const float*)d_in[21];
  const float* fWgs   = (const float*)d_in[22];
  const float* fbgs   = (const float*)d_in[23];
  const float* fgam   = (const float*)d_in[24];
  const float* fbet   = (const float*)d_in[25];

  float* ws_he  = (float*)d_ws;          // [128][128] he_pre accumulator
  float* ws_res = ws_he + 16384;         // [128][128] res_pre accumulator
  float* ws_w   = ws_res + 16384;        // [128][32]  softmax weights
  u16*   ws_wT  = (u16*)(ws_w + 4096);   // [32][4][128][128] bf16 transposed weights (4 MB)

  hipMemsetAsync(d_ws, 0, 32768 * sizeof(float), stream);              // he+res accumulators
  hipMemsetAsync(d_out, 0, (size_t)out_size * sizeof(float), stream);  // output accumulator
  k0_prep<<<128, 128, 0, stream>>>(fWe, fWl, fWgl, fWgs, ws_wT);
  k1_bigmm<<<256, 512, 0, stream>>>(inp, cWe, cWp, ws_he, ws_res);
  k1b_small<<<128, 128, 0, stream>>>(stat, cWe, cbe, cWl, cbl, cWgl, cbgl, cWgs, cbgs,
                                     cgamma, cbeta, cWp, cbp, Ws, bs, ws_he, ws_res, ws_w);
  k2_grn<<<4096, 256, 0, stream>>>(inp, ws_wT, fbe, fbl, fbgl, fbgs,
                                   fgam, fbet, ws_w, (float*)d_out);
}

// Round 3
// 575.038 us; speedup vs baseline: 1.3006x; 1.3006x over previous
//
#include <hip/hip_runtime.h>

// VariableSelection (TFT-style) on gfx950. ALL I/O f32; bf16 MFMA internally.
// B=128 S=64 F=32 D=128 U=128 DS=128 DIN=262272, KMAIN=S*F*D=262144
// R3: k2 f-grouped register combine (atomics /8), k1 16-wave E/P split + LDS dbuf,
//     k1b 4-way split dot chains.

typedef unsigned short u16;
typedef __attribute__((ext_vector_type(4))) u16 u16x4;
typedef __attribute__((ext_vector_type(8))) u16 u16x8;
typedef __attribute__((ext_vector_type(8))) __bf16 bf16x8;
typedef __attribute__((ext_vector_type(4))) float f32x4;

__device__ __forceinline__ u16 f2bf(float f) {
  unsigned int x = __float_as_uint(f);
  return (u16)((x + 0x7fffu + ((x >> 16) & 1u)) >> 16);  // RNE
}
__device__ __forceinline__ float eluf(float x) { return x > 0.f ? x : __expf(x) - 1.f; }
__device__ __forceinline__ float sigmoidf_(float x) { return 1.f / (1.f + __expf(-x)); }

#define MFMA_BF16(a, b, c) __builtin_amdgcn_mfma_f32_16x16x32_bf16((a), (b), (c), 0, 0, 0)

// ---------------------------------------------------------------------------
// K0: convert per-feature GRN weights f32 -> bf16, transposed [n][k].
// grid 128 = f*4+mat, block 128 (thread = n)
// ---------------------------------------------------------------------------
__global__ __launch_bounds__(128) void k0_prep(
    const float* __restrict__ fWe, const float* __restrict__ fWl,
    const float* __restrict__ fWgl, const float* __restrict__ fWgs,
    u16* __restrict__ wT)
{
  const int b = blockIdx.x, f = b >> 2, mat = b & 3;
  const float* srcs[4] = {fWe, fWl, fWgl, fWgs};
  const float* src = srcs[mat] + (size_t)f * 16384;   // [k=128][n=128]
  u16* dst = wT + (size_t)b * 16384;                  // [n=128][k=128]
  const int n = threadIdx.x;
  for (int k8 = 0; k8 < 16; ++k8) {
    u16x8 p;
#pragma unroll
    for (int j = 0; j < 8; ++j) p[j] = f2bf(src[(k8 * 8 + j) * 128 + n]);
    *(u16x8*)&dst[n * 128 + k8 * 8] = p;
  }
}

// ---------------------------------------------------------------------------
// K1: fused split-K  he_pre = v[:, :262144] @ cWe,  res_pre = v @ cWp
// grid 256 k-blocks; block 1024 thr (16 waves): waves 0-7 -> E, 8-15 -> P.
// Double-buffered LDS; one barrier per K-iter; loads issued before MFMA block.
// ---------------------------------------------------------------------------
__global__ __launch_bounds__(1024) void k1_bigmm(
    const float* __restrict__ inp, const float* __restrict__ cWe,
    const float* __restrict__ cWp, float* __restrict__ outE, float* __restrict__ outP)
{
  __shared__ __align__(16) u16 xA[2][128][72];   // v tile [m][k=64] bf16
  __shared__ __align__(16) u16 wE[2][128][72];   // cWe tile transposed [n][k]
  __shared__ __align__(16) u16 wP[2][128][72];   // cWp tile transposed [n][k]
  const int t = threadIdx.x;
  const int lane = t & 63, wv = t >> 6, quad = lane >> 4, l16 = lane & 15;
  const int mat = wv >> 3, wvm = wv & 7;         // compute role
  const int wt = t & 511, wmi = t >> 9;          // staging role: matrix wmi
  const int k4g = wt >> 5, nb4 = wt & 31;        // W micro-tile: 4k x 4n
  const float* Wm = wmi ? cWp : cWe;

  f32x4 acc[8];
#pragma unroll
  for (int n = 0; n < 8; ++n)
#pragma unroll
    for (int r = 0; r < 4; ++r) acc[n][r] = 0.f;

  const size_t kbase = (size_t)blockIdx.x * 1024;

  float4 avr[2], wvr[4];
  // ---- load iter's tile into regs (issue only)
  auto load_regs = [&](int it) {
    const size_t kk = kbase + (size_t)it * 64;
#pragma unroll
    for (int i = 0; i < 2; ++i) {
      const int idx = t + i * 1024;
      const int row = idx >> 4, fo = idx & 15;
      avr[i] = *(const float4*)(inp + (size_t)row * 262144 + kk + fo * 4);
    }
#pragma unroll
    for (int j = 0; j < 4; ++j)
      wvr[j] = *(const float4*)(Wm + (kk + (size_t)(k4g * 4 + j)) * 128 + nb4 * 4);
  };
  // ---- convert + store regs into LDS buffer
  auto store_lds = [&](int buf) {
#pragma unroll
    for (int i = 0; i < 2; ++i) {
      const int idx = t + i * 1024;
      const int row = idx >> 4, fo = idx & 15;
      u16x4 p; p[0] = f2bf(avr[i].x); p[1] = f2bf(avr[i].y);
      p[2] = f2bf(avr[i].z); p[3] = f2bf(avr[i].w);
      *(u16x4*)&xA[buf][row][fo * 4] = p;
    }
    u16 (*Wl)[72] = wmi ? wP[buf] : wE[buf];
#pragma unroll
    for (int c = 0; c < 4; ++c) {
      u16x4 col;
      col[0] = f2bf(((const float*)&wvr[0])[c]);
      col[1] = f2bf(((const float*)&wvr[1])[c]);
      col[2] = f2bf(((const float*)&wvr[2])[c]);
      col[3] = f2bf(((const float*)&wvr[3])[c]);
      *(u16x4*)&Wl[nb4 * 4 + c][k4g * 4] = col;
    }
  };

  load_regs(0);
  store_lds(0);
  for (int it = 0; it < 16; ++it) {
    const int buf = it & 1;
    __syncthreads();
    if (it < 15) load_regs(it + 1);       // global loads in flight during MFMA
    u16 (*Wb)[72] = mat ? wP[buf] : wE[buf];
#pragma unroll
    for (int ks = 0; ks < 2; ++ks) {
      const int ko = ks * 32 + quad * 8;
      const bf16x8 a = *(const bf16x8*)&xA[buf][16 * wvm + l16][ko];
#pragma unroll
      for (int nt = 0; nt < 8; ++nt) {
        const bf16x8 b = *(const bf16x8*)&Wb[nt * 16 + l16][ko];
        acc[nt] = MFMA_BF16(a, b, acc[nt]);
      }
    }
    if (it < 15) store_lds(buf ^ 1);      // vmcnt wait lands after MFMA block
  }
  // C/D layout: col = lane&15, row = quad*4 + reg
  float* outp = mat ? outP : outE;
#pragma unroll
  for (int nt = 0; nt < 8; ++nt) {
    const int col = nt * 16 + l16;
#pragma unroll
    for (int r = 0; r < 4; ++r) {
      const int row = 16 * wvm + quad * 4 + r;
      atomicAdd(&outp[row * 128 + col], acc[nt][r]);
    }
  }
}

// ---------------------------------------------------------------------------
// K1b: static tail + concat-GRN chain + LN + softmax -> w[B,F]
// grid 128 (block = batch row), block 512: u = t&127, dc = t>>7 splits d-loops 4x
// ---------------------------------------------------------------------------
__global__ __launch_bounds__(512) void k1b_small(
    const float* __restrict__ stat,
    const float* __restrict__ cWe, const float* __restrict__ cbe,
    const float* __restrict__ cWl, const float* __restrict__ cbl,
    const float* __restrict__ cWgl, const float* __restrict__ cbgl,
    const float* __restrict__ cWgs, const float* __restrict__ cbgs,
    const float* __restrict__ cgam, const float* __restrict__ cbet,
    const float* __restrict__ cWp, const float* __restrict__ cbp,
    const float* __restrict__ Ws, const float* __restrict__ bs,
    const float* __restrict__ preE, const float* __restrict__ preP,
    float* __restrict__ wout)
{
  const int b = blockIdx.x, t = threadIdx.x;
  const int u = t & 127, dc = t >> 7;
  __shared__ float shS[128], shA[128], shB[128], par[8][132], red[4];
  if (t < 128) shS[t] = stat[b * 128 + t];
  __syncthreads();

  const float* we = cWe + (size_t)262144 * 128;
  const float* wp = cWp + (size_t)262144 * 128;
  float hp = 0.f, rp = 0.f;
  for (int d = dc * 32; d < dc * 32 + 32; ++d) {
    const float sv = shS[d];
    hp += sv * we[d * 128 + u];
    rp += sv * wp[d * 128 + u];
  }
  par[dc][u] = hp; par[4 + dc][u] = rp;
  __syncthreads();

  float rs = 0.f;
  if (t < 128) {
    const float he = preE[b * 128 + t] + cbe[t] + par[0][t] + par[1][t] + par[2][t] + par[3][t];
    rs = preP[b * 128 + t] + cbp[t] + par[4][t] + par[5][t] + par[6][t] + par[7][t];
    shA[t] = eluf(he);
  }
  __syncthreads();

  float p = 0.f;
  for (int d = dc * 32; d < dc * 32 + 32; ++d) p += shA[d] * cWl[d * 128 + u];
  par[dc][u] = p;
  __syncthreads();
  if (t < 128) shB[t] = cbl[t] + par[0][t] + par[1][t] + par[2][t] + par[3][t];
  __syncthreads();

  float gp = 0.f, sp = 0.f;
  for (int d = dc * 32; d < dc * 32 + 32; ++d) {
    const float hv = shB[d];
    gp += hv * cWgl[d * 128 + u];
    sp += hv * cWgs[d * 128 + u];
  }
  par[dc][u] = gp; par[4 + dc][u] = sp;
  __syncthreads();

  float z = 0.f;
  if (t < 128) {
    const float gl = cbgl[t] + par[0][t] + par[1][t] + par[2][t] + par[3][t];
    const float gs = cbgs[t] + par[4][t] + par[5][t] + par[6][t] + par[7][t];
    z = rs + gl * sigmoidf_(gs);
  }
  float s = z, q = z * z;
#pragma unroll
  for (int off = 32; off >= 1; off >>= 1) { s += __shfl_xor(s, off); q += __shfl_xor(q, off); }
  if ((t & 63) == 0 && t < 128) { red[(t >> 6) * 2] = s; red[(t >> 6) * 2 + 1] = q; }
  __syncthreads();
  if (t < 128) {
    const float S = red[0] + red[2], Q = red[1] + red[3];
    const float mean = S * (1.f / 128.f);
    const float var = Q * (1.f / 128.f) - mean * mean;
    const float rstd = rsqrtf(var + 1e-3f);
    shA[t] = (z - mean) * rstd * cgam[t] + cbet[t];
  }
  __syncthreads();
  if (t < 32) {
    float sj = bs[t];
    for (int uu = 0; uu < 128; ++uu) sj += shA[uu] * Ws[uu * 32 + t];
    float m = sj;
#pragma unroll
    for (int off = 16; off >= 1; off >>= 1) m = fmaxf(m, __shfl_xor(m, off));
    const float e = __expf(sj - m);
    float se = e;
#pragma unroll
    for (int off = 16; off >= 1; off >>= 1) se += __shfl_xor(se, off);
    wout[b * 32 + t] = e / se;
  }
}

// ---------------------------------------------------------------------------
// K2 helpers
// ---------------------------------------------------------------------------
__device__ __forceinline__ void stage_wt(const u16* __restrict__ src, int kh,
                                         u16 WT[][72], int t)
{
  // src: pre-transposed bf16 [n=128][k=128]; copy k-half kh into WT[n][0..63]
#pragma unroll
  for (int i = 0; i < 4; ++i) {
    const int u = t + i * 256;
    const int n = u >> 3, k8 = u & 7;
    *(u16x8*)&WT[n][k8 * 8] = *(const u16x8*)(src + n * 128 + kh + k8 * 8);
  }
}

__device__ __forceinline__ void mm_half(const u16 A[][136], const u16 WT[][72],
                                        int wv, int quad, int l16, int kh, f32x4 acc[8])
{
#pragma unroll
  for (int ks = 0; ks < 2; ++ks) {
    const int kol = ks * 32 + quad * 8;
    const bf16x8 a = *(const bf16x8*)&A[16 * wv + l16][kh + kol];
#pragma unroll
    for (int nt = 0; nt < 8; ++nt) {
      const bf16x8 b = *(const bf16x8*)&WT[nt * 16 + l16][kol];
      acc[nt] = MFMA_BF16(a, b, acc[nt]);
    }
  }
}

// ---------------------------------------------------------------------------
// K2: per-feature GRN + LN + weighted combine over an 8-feature group held in
// registers; one atomicAdd per element per block (4 blocks/element total).
// grid 512 = fg(4, slow) x bb(128, fast); block 256 thr; M=64 rows, N=128.
// wave wv owns rows 16wv..16wv+15 (full row per lane-quad -> shuffle LN).
// ---------------------------------------------------------------------------
__global__ __launch_bounds__(256) void k2_grn(
    const float* __restrict__ inp, const u16* __restrict__ wT,
    const float* __restrict__ fbe, const float* __restrict__ fbl,
    const float* __restrict__ fbgl, const float* __restrict__ fbgs,
    const float* __restrict__ fgam, const float* __restrict__ fbet,
    const float* __restrict__ wsel, float* __restrict__ out)
{
  __shared__ __align__(16) u16 xA[64][136];   // x tile bf16
  __shared__ __align__(16) u16 hA[64][136];   // h then h2
  __shared__ __align__(16) u16 WT[128][72];   // weight k-half, transposed [n][k]
  const int t = threadIdx.x;
  const int lane = t & 63, wv = t >> 6, quad = lane >> 4, l16 = lane & 15;
  const int bb = blockIdx.x & 127, fg = blockIdx.x >> 7;

  f32x4 acc[8], glr[8], racc[8];
#pragma unroll
  for (int n = 0; n < 8; ++n)
#pragma unroll
    for (int r = 0; r < 4; ++r) racc[n][r] = 0.f;

#define ZERO_ACC() do { _Pragma("unroll") \
  for (int n_ = 0; n_ < 8; ++n_) { acc[n_][0]=0.f; acc[n_][1]=0.f; acc[n_][2]=0.f; acc[n_][3]=0.f; } } while (0)

  for (int fi = 0; fi < 8; ++fi) {
    const int f = fg * 8 + fi;
    const float wb = wsel[bb * 32 + f];
    const u16* wf = wT + (size_t)f * 65536;   // 4 mats x [128][128]

    __syncthreads();  // previous iteration's xA/WT readers done
    // stage x tile rows 0..63 of batch-row bb, cols f*128..+128 (f32 -> bf16)
#pragma unroll
    for (int i = 0; i < 8; ++i) {
      const int u = t + i * 256;
      const int row = u >> 5, fo = u & 31;
      const float4 v = *(const float4*)(inp + (size_t)(bb * 64 + row) * 4096 + f * 128 + fo * 4);
      u16x4 p; p[0] = f2bf(v.x); p[1] = f2bf(v.y); p[2] = f2bf(v.z); p[3] = f2bf(v.w);
      *(u16x4*)&xA[row][fo * 4] = p;
    }

    // ---- stage 1: h = elu(x @ We + be) -> hA
    stage_wt(wf, 0, WT, t);
    __syncthreads();
    ZERO_ACC();
    mm_half(xA, WT, wv, quad, l16, 0, acc);
    __syncthreads();
    stage_wt(wf, 64, WT, t);
    __syncthreads();
    mm_half(xA, WT, wv, quad, l16, 64, acc);
#pragma unroll
    for (int nt = 0; nt < 8; ++nt) {
      const int col = nt * 16 + l16;
      const float bv = fbe[f * 128 + col];
#pragma unroll
      for (int r = 0; r < 4; ++r)
        hA[16 * wv + quad * 4 + r][col] = f2bf(eluf(acc[nt][r] + bv));
    }
    __syncthreads();

    // ---- stage 2: h2 = h @ Wl + bl -> hA
    stage_wt(wf + 16384, 0, WT, t);
    __syncthreads();
    ZERO_ACC();
    mm_half(hA, WT, wv, quad, l16, 0, acc);
    __syncthreads();
    stage_wt(wf + 16384, 64, WT, t);
    __syncthreads();
    mm_half(hA, WT, wv, quad, l16, 64, acc);
#pragma unroll
    for (int nt = 0; nt < 8; ++nt) {
      const int col = nt * 16 + l16;
      const float bv = fbl[f * 128 + col];
#pragma unroll
      for (int r = 0; r < 4; ++r)
        hA[16 * wv + quad * 4 + r][col] = f2bf(acc[nt][r] + bv);
    }
    __syncthreads();

    // ---- stage 3: gl = h2 @ Wgl + bgl (regs)
    stage_wt(wf + 2 * 16384, 0, WT, t);
    __syncthreads();
    ZERO_ACC();
    mm_half(hA, WT, wv, quad, l16, 0, acc);
    __syncthreads();
    stage_wt(wf + 2 * 16384, 64, WT, t);
    __syncthreads();
    mm_half(hA, WT, wv, quad, l16, 64, acc);
#pragma unroll
    for (int nt = 0; nt < 8; ++nt) {
      const int col = nt * 16 + l16;
      const float bv = fbgl[f * 128 + col];
#pragma unroll
      for (int r = 0; r < 4; ++r) glr[nt][r] = acc[nt][r] + bv;
    }
    __syncthreads();

    // ---- stage 4: gs = h2 @ Wgs + bgs
    stage_wt(wf + 3 * 16384, 0, WT, t);
    __syncthreads();
    ZERO_ACC();
    mm_half(hA, WT, wv, quad, l16, 0, acc);
    __syncthreads();
    stage_wt(wf + 3 * 16384, 64, WT, t);
    __syncthreads();
    mm_half(hA, WT, wv, quad, l16, 64, acc);

    // ---- epilogue: g = gl*sigmoid(gs); z = x + g; LN per row; racc += wb*xg
#pragma unroll
    for (int nt = 0; nt < 8; ++nt) {
      const int col = nt * 16 + l16;
      const float bv = fbgs[f * 128 + col];
#pragma unroll
      for (int r = 0; r < 4; ++r) {
        const float g = glr[nt][r] * sigmoidf_(acc[nt][r] + bv);
        const float x = __uint_as_float(((unsigned int)xA[16 * wv + quad * 4 + r][col]) << 16);
        acc[nt][r] = x + g;  // z
      }
    }
    float sm[4], sq[4];
#pragma unroll
    for (int r = 0; r < 4; ++r) {
      float s = 0.f, q = 0.f;
#pragma unroll
      for (int nt = 0; nt < 8; ++nt) { const float zz = acc[nt][r]; s += zz; q += zz * zz; }
      sm[r] = s; sq[r] = q;
    }
#pragma unroll
    for (int off = 1; off <= 8; off <<= 1)
#pragma unroll
      for (int r = 0; r < 4; ++r) { sm[r] += __shfl_xor(sm[r], off); sq[r] += __shfl_xor(sq[r], off); }
#pragma unroll
    for (int r = 0; r < 4; ++r) {
      const float mean = sm[r] * (1.f / 128.f);
      const float var = sq[r] * (1.f / 128.f) - mean * mean;
      const float rstd = rsqrtf(var + 1e-3f);
      sm[r] = mean; sq[r] = rstd;
    }
#pragma unroll
    for (int nt = 0; nt < 8; ++nt) {
      const int col = nt * 16 + l16;
      const float gam = fgam[f * 128 + col];
      const float bet = fbet[f * 128 + col];
#pragma unroll
      for (int r = 0; r < 4; ++r) {
        const float xg = (acc[nt][r] - sm[r]) * sq[r] * gam + bet;
        racc[nt][r] += wb * xg;
      }
    }
  }

  // ---- one atomic per element per block (4 fg-blocks sum per element)
#pragma unroll
  for (int nt = 0; nt < 8; ++nt) {
    const int col = nt * 16 + l16;
#pragma unroll
    for (int r = 0; r < 4; ++r) {
      const int grow = bb * 64 + 16 * wv + quad * 4 + r;
      atomicAdd(&out[(size_t)grow * 128 + col], racc[nt][r]);
    }
  }
#undef ZERO_ACC
}

extern "C" void kernel_launch(void* const* d_in, const int* in_sizes, int n_in,
                              void* d_out, int out_size, void* d_ws, size_t ws_size,
                              hipStream_t stream)
{
  const float* inp    = (const float*)d_in[0];
  const float* stat   = (const float*)d_in[1];
  const float* cWe    = (const float*)d_in[2];
  const float* cbe    = (const float*)d_in[3];
  const float* cWl    = (const float*)d_in[4];
  const float* cbl    = (const float*)d_in[5];
  const float* cWgl   = (const float*)d_in[6];
  const float* cbgl   = (const float*)d_in[7];
  const float* cWgs   = (const float*)d_in[8];
  const float* cbgs   = (const float*)d_in[9];
  const float* cgamma = (const float*)d_in[10];
  const float* cbeta  = (const float*)d_in[11];
  const float* cWp    = (const float*)d_in[12];
  const float* cbp    = (const float*)d_in[13];
  const float* Ws     = (const float*)d_in[14];
  const float* bs     = (const float*)d_in[15];
  const float* fWe    = (const float*)d_in[16];
  const float* fbe    = (const float*)d_in[17];
  const float* fWl    = (const float*)d_in[18];
  const float* fbl    = (const float*)d_in[19];
  const float* fWgl   = (const float*)d_in[20];
  const float* fbgl   = (const float*)d_in[21];
  const float* fWgs   = (const float*)d_in[22];
  const float* fbgs   = (const float*)d_in[23];
  const float* fgam   = (const float*)d_in[24];
  const float* fbet   = (const float*)d_in[25];

  float* ws_he  = (float*)d_ws;          // [128][128] he_pre accumulator
  float* ws_res = ws_he + 16384;         // [128][128] res_pre accumulator
  float* ws_w   = ws_res + 16384;        // [128][32]  softmax weights
  u16*   ws_wT  = (u16*)(ws_w + 4096);   // [32][4][128][128] bf16 transposed weights (4 MB)

  hipMemsetAsync(d_ws, 0, 32768 * sizeof(float), stream);              // he+res accumulators
  hipMemsetAsync(d_out, 0, (size_t)out_size * sizeof(float), stream);  // output accumulator
  k0_prep<<<128, 128, 0, stream>>>(fWe, fWl, fWgl, fWgs, ws_wT);
  k1_bigmm<<<256, 1024, 0, stream>>>(inp, cWe, cWp, ws_he, ws_res);
  k1b_small<<<128, 512, 0, stream>>>(stat, cWe, cbe, cWl, cbl, cWgl, cbgl, cWgs, cbgs,
                                     cgamma, cbeta, cWp, cbp, Ws, bs, ws_he, ws_res, ws_w);
  k2_grn<<<512, 256, 0, stream>>>(inp, ws_wT, fbe, fbl, fbgl, fbgs,
                                  fgam, fbet, ws_w, (float*)d_out);
}